// Round 2
// baseline (692.707 us; speedup 1.0000x reference)
//
#include <hip/hip_runtime.h>
#include <hip/hip_bf16.h>

// Arctic MoE: B=1 S=2048 H=1024 F=4096 E=8 TOPK=2, fp32 in/out, bf16 MFMA compute.
// Top-2 dispatch (4x FLOP cut vs dense reference; identical math since
// combine==0 for unselected experts).

constexpr int kS = 2048;
constexpr int kH = 1024;
constexpr int kF = 4096;
constexpr int kE = 8;

typedef __attribute__((ext_vector_type(8))) short bf16x8;
typedef __attribute__((ext_vector_type(4))) float f32x4;

#define GLOAD16(gp, lp)                                                        \
  __builtin_amdgcn_global_load_lds(                                            \
      (const __attribute__((address_space(1))) void*)(gp),                     \
      (__attribute__((address_space(3))) void*)(lp), 16, 0, 0)

// ---------------------------------------------------------------- router
__global__ __launch_bounds__(64) void moe_router(
    const float* __restrict__ x, const float* __restrict__ Wg,
    float* __restrict__ logits_out, __hip_bfloat16* __restrict__ xbf,
    int* __restrict__ list, float* __restrict__ wtl, int* __restrict__ cnt) {
  int s = blockIdx.x;
  int l = threadIdx.x;
  const float* xr = x + (size_t)s * kH;
  float acc[kE];
#pragma unroll
  for (int e = 0; e < kE; ++e) acc[e] = 0.f;
#pragma unroll
  for (int j = 0; j < kH / 64; ++j) {
    int i = j * 64 + l;
    float xv = xr[i];
    xbf[(size_t)s * kH + i] = __float2bfloat16(xv);
    const float* wr = Wg + (size_t)i * kE;
#pragma unroll
    for (int e = 0; e < kE; ++e) acc[e] += xv * wr[e];
  }
#pragma unroll
  for (int off = 32; off > 0; off >>= 1) {
#pragma unroll
    for (int e = 0; e < kE; ++e) acc[e] += __shfl_xor(acc[e], off);
  }
  if (l == 0) {
    float* lo = logits_out + (size_t)s * kE;
#pragma unroll
    for (int e = 0; e < kE; ++e) lo[e] = acc[e];
    int e0 = 0;
    float b0 = acc[0];
    for (int e = 1; e < kE; ++e)
      if (acc[e] > b0) { b0 = acc[e]; e0 = e; }
    int e1 = -1;
    float b1 = -3.0e38f;
    for (int e = 0; e < kE; ++e)
      if (e != e0 && acc[e] > b1) { b1 = acc[e]; e1 = e; }
    float w0 = 1.f / (1.f + __expf(b1 - b0));  // softmax over {b0,b1}
    float w1 = 1.f - w0;
    int p0 = atomicAdd(&cnt[e0], 1);
    list[e0 * kS + p0] = s;
    wtl[e0 * kS + p0] = w0;
    int p1 = atomicAdd(&cnt[e1], 1);
    list[e1 * kS + p1] = s;
    wtl[e1 * kS + p1] = w1;
  }
}

__global__ void moe_prefix(const int* __restrict__ cnt, int* __restrict__ offs) {
  if (threadIdx.x == 0) {
    int a = 0;
    for (int e = 0; e < kE; ++e) { offs[e] = a; a += cnt[e]; }
    offs[kE] = a;
  }
}

// ---------------------------------------------------- transpose + cvt to bf16
// src: [E][R][C] f32 row-major  ->  dst: [E][C][R] bf16 (K-contiguous MFMA B)
__global__ __launch_bounds__(256) void moe_tcvt(
    const float* __restrict__ src, __hip_bfloat16* __restrict__ dst, int R, int C) {
  __shared__ float tile[64][65];
  int e = blockIdx.z;
  int r0 = blockIdx.y * 64, c0 = blockIdx.x * 64;
  int t = threadIdx.x;
  int tr = t >> 4, tc4 = (t & 15) * 4;
  const float* sp = src + ((size_t)e * R + r0) * C + c0;
#pragma unroll
  for (int it = 0; it < 4; ++it) {
    int r = it * 16 + tr;
    float4 v = *(const float4*)(sp + (size_t)r * C + tc4);
    tile[r][tc4 + 0] = v.x;
    tile[r][tc4 + 1] = v.y;
    tile[r][tc4 + 2] = v.z;
    tile[r][tc4 + 3] = v.w;
  }
  __syncthreads();
  __hip_bfloat16* dp = dst + ((size_t)e * C + c0) * R + r0;
#pragma unroll
  for (int it = 0; it < 4; ++it) {
    int c = it * 16 + tr;
    unsigned short pk[4];
#pragma unroll
    for (int j = 0; j < 4; ++j) {
      __hip_bfloat16 bv = __float2bfloat16(tile[tc4 + j][c]);
      pk[j] = *(unsigned short*)&bv;
    }
    *(uint2*)(dp + (size_t)c * R + tc4) = *(uint2*)pk;
  }
}

// ------------------------------------------------- stage 1: h = silu(xW1)*(xW3)
__global__ __launch_bounds__(256) void moe_ffn1(
    const __hip_bfloat16* __restrict__ xbf, const __hip_bfloat16* __restrict__ w1t,
    const __hip_bfloat16* __restrict__ w3t, __hip_bfloat16* __restrict__ hbuf,
    const int* __restrict__ list, const int* __restrict__ cnt,
    const int* __restrict__ offs) {
  int e = blockIdx.z, mtile = blockIdx.y, ntile = blockIdx.x;
  int c = cnt[e];
  if (mtile * 128 >= c) return;
  __shared__ __align__(16) __hip_bfloat16 As[128 * 32];
  __shared__ __align__(16) __hip_bfloat16 B1s[64 * 32];
  __shared__ __align__(16) __hip_bfloat16 B3s[64 * 32];
  int t = threadIdx.x, l = t & 63, wv = t >> 6;
  int base = offs[e];
  int kq = l & 3;
  int tokb[2];
#pragma unroll
  for (int ci = 0; ci < 2; ++ci) {
    int r = (wv * 2 + ci) * 16 + (l >> 2);
    int gp = mtile * 128 + r;
    int gpc = gp < c ? gp : c - 1;
    tokb[ci] = list[e * kS + gpc];
  }
  const char* xg = (const char*)xbf;
  const char* gA0 = xg + ((size_t)tokb[0] * kH + kq * 8) * 2;
  const char* gA1 = xg + ((size_t)tokb[1] * kH + kq * 8) * 2;
  int fb = ntile * 64 + wv * 16 + (l >> 2);
  const char* gB1 =
      (const char*)(w1t + (size_t)e * kF * kH) + ((size_t)fb * kH + kq * 8) * 2;
  const char* gB3 =
      (const char*)(w3t + (size_t)e * kF * kH) + ((size_t)fb * kH + kq * 8) * 2;
  char* lA0 = (char*)As + (wv * 2 + 0) * 1024;
  char* lA1 = (char*)As + (wv * 2 + 1) * 1024;
  char* lB1 = (char*)B1s + wv * 1024;
  char* lB3 = (char*)B3s + wv * 1024;

  int wr = wv >> 1, wc = wv & 1;
  f32x4 acc1[4][2], acc3[4][2];
#pragma unroll
  for (int mi = 0; mi < 4; ++mi)
#pragma unroll
    for (int ni = 0; ni < 2; ++ni) {
      acc1[mi][ni] = (f32x4){0.f, 0.f, 0.f, 0.f};
      acc3[mi][ni] = (f32x4){0.f, 0.f, 0.f, 0.f};
    }

  for (int kk = 0; kk < kH / 32; ++kk) {
    size_t ko = (size_t)kk * 64;  // 32 bf16 per K-step
    GLOAD16(gA0 + ko, lA0);
    GLOAD16(gA1 + ko, lA1);
    GLOAD16(gB1 + ko, lB1);
    GLOAD16(gB3 + ko, lB3);
    asm volatile("s_waitcnt vmcnt(0)" ::: "memory");
    __syncthreads();
    bf16x8 a[4], b1[2], b3[2];
#pragma unroll
    for (int mi = 0; mi < 4; ++mi) {
      int row = wr * 64 + mi * 16 + (l & 15);
      a[mi] = *(const bf16x8*)(As + row * 32 + (l >> 4) * 8);
    }
#pragma unroll
    for (int ni = 0; ni < 2; ++ni) {
      int fr = wc * 32 + ni * 16 + (l & 15);
      b1[ni] = *(const bf16x8*)(B1s + fr * 32 + (l >> 4) * 8);
      b3[ni] = *(const bf16x8*)(B3s + fr * 32 + (l >> 4) * 8);
    }
#pragma unroll
    for (int mi = 0; mi < 4; ++mi)
#pragma unroll
      for (int ni = 0; ni < 2; ++ni) {
        acc1[mi][ni] = __builtin_amdgcn_mfma_f32_16x16x32_bf16(
            a[mi], b1[ni], acc1[mi][ni], 0, 0, 0);
        acc3[mi][ni] = __builtin_amdgcn_mfma_f32_16x16x32_bf16(
            a[mi], b3[ni], acc3[mi][ni], 0, 0, 0);
      }
    __syncthreads();
  }
#pragma unroll
  for (int mi = 0; mi < 4; ++mi) {
#pragma unroll
    for (int j = 0; j < 4; ++j) {
      int p = wr * 64 + mi * 16 + (l >> 4) * 4 + j;
      int gp = mtile * 128 + p;
      if (gp < c) {
        size_t slot = (size_t)(base + gp);
#pragma unroll
        for (int ni = 0; ni < 2; ++ni) {
          int f = ntile * 64 + wc * 32 + ni * 16 + (l & 15);
          float v1 = acc1[mi][ni][j], v3 = acc3[mi][ni][j];
          float hs = v1 / (1.f + __expf(-v1)) * v3;
          hbuf[slot * kF + f] = __float2bfloat16(hs);
        }
      }
    }
  }
}

// -------------------------------------------- stage 2: out += w * (h @ W2)
__global__ __launch_bounds__(256) void moe_ffn2(
    const __hip_bfloat16* __restrict__ hbuf, const __hip_bfloat16* __restrict__ w2t,
    float* __restrict__ out, const int* __restrict__ list,
    const float* __restrict__ wtl, const int* __restrict__ cnt,
    const int* __restrict__ offs) {
  int e = blockIdx.z, mtile = blockIdx.y, ntile = blockIdx.x;
  int c = cnt[e];
  if (mtile * 64 >= c) return;
  __shared__ __align__(16) __hip_bfloat16 As[64 * 32];
  __shared__ __align__(16) __hip_bfloat16 Bs[64 * 32];
  int t = threadIdx.x, l = t & 63, wv = t >> 6;
  int base = offs[e];
  int kq = l & 3;
  int ra = wv * 16 + (l >> 2);
  int gpa = mtile * 64 + ra;
  if (gpa >= c) gpa = c - 1;  // clamp reads into valid compact rows
  const char* gA =
      (const char*)hbuf + (((size_t)(base + gpa)) * kF + kq * 8) * 2;
  int nb = ntile * 64 + wv * 16 + (l >> 2);
  const char* gB =
      (const char*)(w2t + (size_t)e * kH * kF) + ((size_t)nb * kF + kq * 8) * 2;
  char* lA = (char*)As + wv * 1024;
  char* lB = (char*)Bs + wv * 1024;
  int wr = wv >> 1, wc = wv & 1;
  f32x4 acc[2][2];
#pragma unroll
  for (int mi = 0; mi < 2; ++mi)
#pragma unroll
    for (int ni = 0; ni < 2; ++ni) acc[mi][ni] = (f32x4){0.f, 0.f, 0.f, 0.f};

  for (int kk = 0; kk < kF / 32; ++kk) {
    size_t ko = (size_t)kk * 64;
    GLOAD16(gA + ko, lA);
    GLOAD16(gB + ko, lB);
    asm volatile("s_waitcnt vmcnt(0)" ::: "memory");
    __syncthreads();
    bf16x8 a[2], b[2];
#pragma unroll
    for (int mi = 0; mi < 2; ++mi) {
      int row = wr * 32 + mi * 16 + (l & 15);
      a[mi] = *(const bf16x8*)(As + row * 32 + (l >> 4) * 8);
    }
#pragma unroll
    for (int ni = 0; ni < 2; ++ni) {
      int row = wc * 32 + ni * 16 + (l & 15);
      b[ni] = *(const bf16x8*)(Bs + row * 32 + (l >> 4) * 8);
    }
#pragma unroll
    for (int mi = 0; mi < 2; ++mi)
#pragma unroll
      for (int ni = 0; ni < 2; ++ni)
        acc[mi][ni] = __builtin_amdgcn_mfma_f32_16x16x32_bf16(
            a[mi], b[ni], acc[mi][ni], 0, 0, 0);
    __syncthreads();
  }
#pragma unroll
  for (int mi = 0; mi < 2; ++mi) {
#pragma unroll
    for (int j = 0; j < 4; ++j) {
      int p = wr * 32 + mi * 16 + (l >> 4) * 4 + j;
      int gp = mtile * 64 + p;
      if (gp < c) {
        int tok = list[e * kS + gp];
        float w = wtl[e * kS + gp];
#pragma unroll
        for (int ni = 0; ni < 2; ++ni) {
          int col = ntile * 64 + wc * 32 + ni * 16 + (l & 15);
          atomicAdd(out + (size_t)tok * kH + col, acc[mi][ni][j] * w);
        }
      }
    }
  }
}

extern "C" void kernel_launch(void* const* d_in, const int* in_sizes, int n_in,
                              void* d_out, int out_size, void* d_ws, size_t ws_size,
                              hipStream_t stream) {
  const float* x = (const float*)d_in[0];
  const float* Wg = (const float*)d_in[1];
  const float* W1 = (const float*)d_in[2];
  const float* W3 = (const float*)d_in[3];
  const float* W2 = (const float*)d_in[4];
  float* out = (float*)d_out;

  // workspace layout (~239.2 MB)
  char* ws = (char*)d_ws;
  __hip_bfloat16* w1t = (__hip_bfloat16*)(ws + 0);
  __hip_bfloat16* w3t = (__hip_bfloat16*)(ws + 67108864);
  __hip_bfloat16* w2t = (__hip_bfloat16*)(ws + 134217728);
  __hip_bfloat16* xbf = (__hip_bfloat16*)(ws + 201326592);
  __hip_bfloat16* hbuf = (__hip_bfloat16*)(ws + 205520896);
  int* list = (int*)(ws + 239075328);
  float* wtl = (float*)(ws + 239140864);
  int* cnt = (int*)(ws + 239206400);
  int* offs = (int*)(ws + 239206432);

  hipMemsetAsync(out, 0, (size_t)kS * kH * sizeof(float), stream);
  hipMemsetAsync(cnt, 0, kE * sizeof(int), stream);

  // W1,W3: [E][H][F] -> [E][F][H] bf16 ; W2: [E][F][H] -> [E][H][F] bf16
  moe_tcvt<<<dim3(kF / 64, kH / 64, kE), 256, 0, stream>>>(W1, w1t, kH, kF);
  moe_tcvt<<<dim3(kF / 64, kH / 64, kE), 256, 0, stream>>>(W3, w3t, kH, kF);
  moe_tcvt<<<dim3(kH / 64, kF / 64, kE), 256, 0, stream>>>(W2, w2t, kF, kH);

  moe_router<<<dim3(kS), 64, 0, stream>>>(x, Wg, out + (size_t)kS * kH, xbf,
                                          list, wtl, cnt);
  moe_prefix<<<1, 64, 0, stream>>>(cnt, offs);

  moe_ffn1<<<dim3(kF / 64, kS / 128, kE), 256, 0, stream>>>(
      xbf, w1t, w3t, hbuf, list, cnt, offs);
  moe_ffn2<<<dim3(kH / 64, kS / 64, kE), 256, 0, stream>>>(
      hbuf, w2t, out, list, wtl, cnt, offs);
}